// Round 12
// baseline (1629.827 us; speedup 1.0000x reference)
//
#include <hip/hip_runtime.h>

typedef __attribute__((ext_vector_type(8))) short bfrag8;   // 8 x bf16 (4 VGPRs)
typedef __attribute__((ext_vector_type(4))) short bfrag4;   // 4 x bf16
typedef __attribute__((ext_vector_type(4))) float facc4;    // 4 x f32 accum

#define DEV_INLINE __device__ __forceinline__

DEV_INLINE short f2bf(float f) {
    union { float f; unsigned u; } x; x.f = f;
    unsigned r = (x.u + 0x7FFFu + ((x.u >> 16) & 1u)) >> 16;
    return (short)r;
}

DEV_INLINE float bf2f(short s) {
    union { unsigned u; float f; } x;
    x.u = ((unsigned)(unsigned short)s) << 16;
    return x.f;
}

DEV_INLINE unsigned pack_bf2(float a, float b) {
    return (unsigned)(unsigned short)f2bf(a) | ((unsigned)(unsigned short)f2bf(b) << 16);
}

// async global->LDS, 16B per lane; dest = wave-uniform base + lane*16
#define GL2LDS(gp, lp) __builtin_amdgcn_global_load_lds( \
    (const __attribute__((address_space(1))) void*)(gp), \
    (__attribute__((address_space(3))) void*)(lp), 16, 0, 0)

#define MFMA16(a, b, c) __builtin_amdgcn_mfma_f32_16x16x32_bf16((a), (b), (c), 0, 0, 0)

// ---------------- embedding gather ----------------
__global__ __launch_bounds__(256) void embed_kernel(const int* __restrict__ ids,
                                                    const float* __restrict__ emb,
                                                    float* __restrict__ h) {
    int s = blockIdx.x;
    int id = ids[s];
    const float* src = emb + (size_t)id * 2048;
    float* dst = h + (size_t)s * 2048;
    int t = threadIdx.x;
    float4 a = *(const float4*)(src + t * 8);
    float4 b = *(const float4*)(src + t * 8 + 4);
    *(float4*)(dst + t * 8) = a;
    *(float4*)(dst + t * 8 + 4) = b;
}

// ---------------- RMSNorm rows of 2048, bf16 out ----------------
__global__ __launch_bounds__(256) void rmsnorm_bf16_kernel(const float* __restrict__ in,
                                                           const float* __restrict__ w,
                                                           short* __restrict__ out) {
    int row = blockIdx.x;
    const float* x = in + (size_t)row * 2048;
    short* y = out + (size_t)row * 2048;
    int t = threadIdx.x;
    float4 a = *(const float4*)(x + t * 8);
    float4 b = *(const float4*)(x + t * 8 + 4);
    float ss = a.x*a.x + a.y*a.y + a.z*a.z + a.w*a.w
             + b.x*b.x + b.y*b.y + b.z*b.z + b.w*b.w;
#pragma unroll
    for (int off = 32; off >= 1; off >>= 1) ss += __shfl_xor(ss, off);
    __shared__ float red[4];
    if ((t & 63) == 0) red[t >> 6] = ss;
    __syncthreads();
    float tot = red[0] + red[1] + red[2] + red[3];
    float sc = rsqrtf(tot * (1.0f / 2048.0f) + 1e-6f);
    float4 wa = *(const float4*)(w + t * 8);
    float4 wb = *(const float4*)(w + t * 8 + 4);
    bfrag8 o;
    o[0] = f2bf(a.x * sc * wa.x); o[1] = f2bf(a.y * sc * wa.y);
    o[2] = f2bf(a.z * sc * wa.z); o[3] = f2bf(a.w * sc * wa.w);
    o[4] = f2bf(b.x * sc * wb.x); o[5] = f2bf(b.y * sc * wb.y);
    o[6] = f2bf(b.z * sc * wb.z); o[7] = f2bf(b.w * sc * wb.w);
    *(bfrag8*)(y + t * 8) = o;
}

// ---------------- weight transpose-convert: W[K][N] f32 -> Wt[N][K] bf16 ----------------
__global__ __launch_bounds__(256) void wconv_kernel(const float* __restrict__ W,
                                                    short* __restrict__ Wt,
                                                    int K, int N) {
    __shared__ short Lt[64][72];
    int k0 = blockIdx.x * 64, n0 = blockIdx.y * 64;
    int tid = threadIdx.x;
    int r = tid >> 4, c = (tid & 15) * 4;
#pragma unroll
    for (int j = 0; j < 4; ++j) {
        int k = r + j * 16;
        float4 v = *(const float4*)(W + (size_t)(k0 + k) * N + n0 + c);
        Lt[c + 0][k] = f2bf(v.x); Lt[c + 1][k] = f2bf(v.y);
        Lt[c + 2][k] = f2bf(v.z); Lt[c + 3][k] = f2bf(v.w);
    }
    __syncthreads();
    int n = tid >> 3, kk = (tid & 7) * 8;
#pragma unroll
    for (int j = 0; j < 2; ++j)
        *(bfrag8*)(Wt + (size_t)(n0 + n + j * 32) * K + k0 + kk) = *(const bfrag8*)&Lt[n + j * 32][kk];
}

// ---------------- GEMM ring-4 256x256 (big-N): C = A * Bt^T ----------------
// 512 thr / 8 waves (2Mx4N), BK=32, 4-slot ring, depth-3 prefetch, counted
// vmcnt(8/4/0), one barrier per tile, chunk-XOR swizzle, setprio. 128KB, 1 blk/CU.
template<int OUT>
__global__ __launch_bounds__(512, 1) void gemmB(const short* __restrict__ A,
                                                const short* __restrict__ Bt,
                                                float* __restrict__ C,
                                                int K, int N) {
    constexpr int ASLOT = 256 * 64;      // bytes per ring slot
    constexpr int BOFF = 4 * ASLOT;
    __shared__ short lds[65536];         // 128 KB
    char* ldsb = (char*)lds;
    int tid = threadIdx.x;
    int lane = tid & 63, wave = tid >> 6;
    int wm = wave >> 2, wn = wave & 3;
    int lr = lane & 15, lg = lane >> 4;

    int gx = gridDim.x;
    int nwg = gx * gridDim.y;
    int b = blockIdx.y * gx + blockIdx.x;
    int q8 = nwg >> 3, r8 = nwg & 7;
    int xcd = b & 7, idx = b >> 3;
    int lb = (xcd < r8) ? (xcd * (q8 + 1) + idx) : (r8 * (q8 + 1) + (xcd - r8) * q8 + idx);
    int bm = (lb % gx) * 256, bn = (lb / gx) * 256;

    facc4 acc[8][4];
#pragma unroll
    for (int m = 0; m < 8; ++m)
#pragma unroll
        for (int n = 0; n < 4; ++n) acc[m][n] = (facc4){0.f, 0.f, 0.f, 0.f};

    int rs = tid >> 2;
    int cs = (tid & 3) ^ ((rs >> 1) & 3);
    const size_t sK = (size_t)K;
    const short* Ag0 = A + (size_t)(bm + rs) * sK + cs * 8;
    const short* Ag1 = A + (size_t)(bm + rs + 128) * sK + cs * 8;
    const short* Bg0 = Bt + (size_t)(bn + rs) * sK + cs * 8;
    const short* Bg1 = Bt + (size_t)(bn + rs + 128) * sK + cs * 8;

    auto stage = [&](int u) {
        int sl = u & 3;
        int ko = u * 32;
        char* Ad = ldsb + sl * ASLOT + tid * 16;
        char* Bd = ldsb + BOFF + sl * ASLOT + tid * 16;
        GL2LDS(Ag0 + ko, Ad);
        GL2LDS(Ag1 + ko, Ad + 8192);
        GL2LDS(Bg0 + ko, Bd);
        GL2LDS(Bg1 + ko, Bd + 8192);
    };

    int NT = K >> 5;
    stage(0); stage(1); stage(2);

    int arow[8], brow[4];
#pragma unroll
    for (int m = 0; m < 8; ++m) arow[m] = wm * 128 + m * 16 + lr;
#pragma unroll
    for (int n = 0; n < 4; ++n) brow[n] = wn * 64 + n * 16 + lr;

    for (int t = 0; t < NT; ++t) {
        if (t < NT - 2)       asm volatile("s_waitcnt vmcnt(8)" ::: "memory");
        else if (t == NT - 2) asm volatile("s_waitcnt vmcnt(4)" ::: "memory");
        else                  asm volatile("s_waitcnt vmcnt(0)" ::: "memory");
        __builtin_amdgcn_s_barrier();
        __builtin_amdgcn_sched_barrier(0);
        const char* Ab = ldsb + (t & 3) * ASLOT;
        const char* Bb = ldsb + BOFF + (t & 3) * ASLOT;
        bfrag8 af[8], bf[4];
#pragma unroll
        for (int m = 0; m < 8; ++m) {
            int r = arow[m];
            af[m] = *(const bfrag8*)(Ab + r * 64 + ((lg ^ ((r >> 1) & 3)) << 4));
        }
#pragma unroll
        for (int n = 0; n < 4; ++n) {
            int r = brow[n];
            bf[n] = *(const bfrag8*)(Bb + r * 64 + ((lg ^ ((r >> 1) & 3)) << 4));
        }
        if (t + 3 < NT) stage(t + 3);
        __builtin_amdgcn_s_setprio(1);
#pragma unroll
        for (int m = 0; m < 8; ++m)
#pragma unroll
            for (int n = 0; n < 4; ++n)
                acc[m][n] = MFMA16(af[m], bf[n], acc[m][n]);
        __builtin_amdgcn_s_setprio(0);
    }

    int crow = bm + wm * 128 + lg * 4;
    int ccol = bn + wn * 64 + lr;
#pragma unroll
    for (int m = 0; m < 8; ++m)
#pragma unroll
        for (int n = 0; n < 4; ++n)
#pragma unroll
            for (int r = 0; r < 4; ++r) {
                size_t ci = (size_t)(crow + m * 16 + r) * N + ccol + n * 16;
                if constexpr (OUT == 0)      C[ci] = acc[m][n][r];
                else if constexpr (OUT == 1) C[ci] = C[ci] + acc[m][n][r];
                else                         ((short*)C)[ci] = f2bf(acc[m][n][r]);
            }
}

// ---------------- GEMM ring-4 128x128, 2 blocks/CU (TLP overlap) ----------------
// 256 thr / 4 waves (2Mx2N), BK=32, 4-slot ring, 64KB LDS. ldk = row stride
// (elements) of A and Bt; K = extent to process (enables split-K).
template<int OUT>
__global__ __launch_bounds__(256, 2) void gemmR(const short* __restrict__ A,
                                                const short* __restrict__ Bt,
                                                float* __restrict__ C,
                                                int K, int ldk, int N) {
    constexpr int ASLOT = 128 * 64;
    constexpr int BOFF = 4 * ASLOT;
    __shared__ short lds[4 * 256 * 32];  // 64 KB
    char* ldsb = (char*)lds;
    int tid = threadIdx.x;
    int lane = tid & 63, wave = tid >> 6;
    int wm = wave >> 1, wn = wave & 1;
    int lr = lane & 15, lg = lane >> 4;

    int gx = gridDim.x;
    int nwg = gx * gridDim.y;
    int b = blockIdx.y * gx + blockIdx.x;
    int q8 = nwg >> 3, r8 = nwg & 7;
    int xcd = b & 7, idx = b >> 3;
    int lb = (xcd < r8) ? (xcd * (q8 + 1) + idx) : (r8 * (q8 + 1) + (xcd - r8) * q8 + idx);
    int bm = (lb % gx) * 128, bn = (lb / gx) * 128;

    facc4 acc[4][4];
#pragma unroll
    for (int m = 0; m < 4; ++m)
#pragma unroll
        for (int n = 0; n < 4; ++n) acc[m][n] = (facc4){0.f, 0.f, 0.f, 0.f};

    int rs = tid >> 2;
    int cs = (tid & 3) ^ ((rs >> 1) & 3);
    const size_t sK = (size_t)ldk;
    const short* Ag0 = A + (size_t)(bm + rs) * sK + cs * 8;
    const short* Ag1 = A + (size_t)(bm + rs + 64) * sK + cs * 8;
    const short* Bg0 = Bt + (size_t)(bn + rs) * sK + cs * 8;
    const short* Bg1 = Bt + (size_t)(bn + rs + 64) * sK + cs * 8;

    auto stage = [&](int u) {
        int sl = u & 3;
        int ko = u * 32;
        char* Ad = ldsb + sl * ASLOT + tid * 16;
        char* Bd = ldsb + BOFF + sl * ASLOT + tid * 16;
        GL2LDS(Ag0 + ko, Ad);
        GL2LDS(Ag1 + ko, Ad + 4096);
        GL2LDS(Bg0 + ko, Bd);
        GL2LDS(Bg1 + ko, Bd + 4096);
    };

    int NT = K >> 5;
    stage(0); stage(1); stage(2);

    int arow[4], brow[4];
#pragma unroll
    for (int m = 0; m < 4; ++m) arow[m] = wm * 64 + m * 16 + lr;
#pragma unroll
    for (int n = 0; n < 4; ++n) brow[n] = wn * 64 + n * 16 + lr;

    for (int t = 0; t < NT; ++t) {
        if (t < NT - 2)       asm volatile("s_waitcnt vmcnt(8)" ::: "memory");
        else if (t == NT - 2) asm volatile("s_waitcnt vmcnt(4)" ::: "memory");
        else                  asm volatile("s_waitcnt vmcnt(0)" ::: "memory");
        __builtin_amdgcn_s_barrier();
        __builtin_amdgcn_sched_barrier(0);
        const char* Ab = ldsb + (t & 3) * ASLOT;
        const char* Bb = ldsb + BOFF + (t & 3) * ASLOT;
        bfrag8 af[4], bf[4];
#pragma unroll
        for (int m = 0; m < 4; ++m) {
            int r = arow[m];
            af[m] = *(const bfrag8*)(Ab + r * 64 + ((lg ^ ((r >> 1) & 3)) << 4));
        }
#pragma unroll
        for (int n = 0; n < 4; ++n) {
            int r = brow[n];
            bf[n] = *(const bfrag8*)(Bb + r * 64 + ((lg ^ ((r >> 1) & 3)) << 4));
        }
        if (t + 3 < NT) stage(t + 3);
        __builtin_amdgcn_s_setprio(1);
#pragma unroll
        for (int m = 0; m < 4; ++m)
#pragma unroll
            for (int n = 0; n < 4; ++n)
                acc[m][n] = MFMA16(af[m], bf[n], acc[m][n]);
        __builtin_amdgcn_s_setprio(0);
    }

    int crow = bm + wm * 64 + lg * 4;
    int ccol = bn + wn * 64 + lr;
#pragma unroll
    for (int m = 0; m < 4; ++m)
#pragma unroll
        for (int n = 0; n < 4; ++n)
#pragma unroll
            for (int r = 0; r < 4; ++r) {
                size_t ci = (size_t)(crow + m * 16 + r) * N + ccol + n * 16;
                if constexpr (OUT == 0)      C[ci] = acc[m][n][r];
                else if constexpr (OUT == 1) C[ci] = C[ci] + acc[m][n][r];
                else                         ((short*)C)[ci] = f2bf(acc[m][n][r]);
            }
}

// ---------------- residual += p0 + p1 (split-K combine) ----------------
__global__ __launch_bounds__(256) void add2_kernel(float* __restrict__ h,
                                                   const float* __restrict__ p0,
                                                   const float* __restrict__ p1) {
    size_t i = ((size_t)blockIdx.x * 256 + threadIdx.x) * 4;
    float4 a = *(const float4*)(h + i);
    float4 x = *(const float4*)(p0 + i);
    float4 y = *(const float4*)(p1 + i);
    a.x += x.x + y.x; a.y += x.y + y.y; a.z += x.z + y.z; a.w += x.w + y.w;
    *(float4*)(h + i) = a;
}

// ---------------- RoPE ----------------
#define ROPE_C 0.20762050593046010f   // log2(10000)/64
#define INV2PI 0.15915494309189535f
#define TWOPI  6.283185307179586f
#define QK_SCALE 0.08838834764831845f // 1/sqrt(128), folded into Q

DEV_INLINE void rope_sc(float pos, int j, float* s, float* c) {
    float f = pos * exp2f(-(float)j * ROPE_C);
    float r = f * INV2PI;
    r -= floorf(r);
    __sincosf(r * TWOPI, s, c);
}

__global__ __launch_bounds__(128) void prep_q_kernel(const float* __restrict__ qkv,
                                                     short* __restrict__ Qb) {
    int h = blockIdx.x, s = blockIdx.y, d = threadIdx.x;
    const float* src = qkv + (size_t)s * 4096 + h * 128;
    float x = src[d], xp = src[d ^ 64];
    float sn, c;
    rope_sc((float)(2048 + s), d & 63, &sn, &c);
    float o = (d < 64) ? (x * c - xp * sn) : (x * c + xp * sn);
    Qb[((size_t)h * 2048 + s) * 128 + d] = f2bf(o * QK_SCALE);
}

__global__ __launch_bounds__(128) void prep_k_kernel(const float* __restrict__ kc,
                                                     const float* __restrict__ qkv,
                                                     short* __restrict__ Kf) {
    int h = blockIdx.x, t = blockIdx.y, d = threadIdx.x;
    float x, xp;
    if (t < 2048) {
        const float* src = kc + ((size_t)h * 2048 + t) * 128;
        x = src[d]; xp = src[d ^ 64];
    } else {
        const float* src = qkv + (size_t)(t - 2048) * 4096 + 2048 + (h >> 1) * 128;
        x = src[d]; xp = src[d ^ 64];
    }
    float sn, c;
    rope_sc((float)t, d & 63, &sn, &c);
    float o = (d < 64) ? (x * c - xp * sn) : (x * c + xp * sn);
    Kf[((size_t)h * 4096 + t) * 128 + d] = f2bf(o);
}

__global__ __launch_bounds__(256) void prep_v_kernel(const float* __restrict__ vc,
                                                     const float* __restrict__ qkv,
                                                     short* __restrict__ Vt) {
    int h = blockIdx.x;
    int t0 = blockIdx.y * 64;
    __shared__ short Lt[128][72];
    int tid = threadIdx.x;
    int r = tid >> 2;
    int c0 = (tid & 3) * 32;
    int t = t0 + r;
    const float* src = (t < 2048)
        ? vc + ((size_t)h * 2048 + t) * 128 + c0
        : qkv + (size_t)(t - 2048) * 4096 + 3072 + (h >> 1) * 128 + c0;
#pragma unroll
    for (int i = 0; i < 32; i += 4) {
        float4 v = *(const float4*)(src + i);
        Lt[c0 + i + 0][r] = f2bf(v.x);
        Lt[c0 + i + 1][r] = f2bf(v.y);
        Lt[c0 + i + 2][r] = f2bf(v.z);
        Lt[c0 + i + 3][r] = f2bf(v.w);
    }
    __syncthreads();
    int d = tid >> 1;
    int hh = (tid & 1) * 32;
    short* dst = Vt + ((size_t)h * 128 + d) * 4096 + t0 + hh;
    const short* srcl = &Lt[d][hh];
#pragma unroll
    for (int i = 0; i < 32; i += 8)
        *(bfrag8*)(dst + i) = *(const bfrag8*)(srcl + i);
}

// ---------------- flash attention v4: KVBLK=64 ----------------
__global__ __launch_bounds__(256, 2) void attn_kernel(const short* __restrict__ Q,
                                                      const short* __restrict__ Kf,
                                                      const short* __restrict__ Vt,
                                                      float* __restrict__ Op,
                                                      float* __restrict__ Ml,
                                                      float* __restrict__ Ll) {
    int h = blockIdx.x;
    int qb = blockIdx.y * 64;
    int z = blockIdx.z;
    int tid = threadIdx.x;
    int lane = tid & 63, wave = tid >> 6;
    int lr = lane & 15, lg = lane >> 4;
    int qrow = qb + wave * 16;
    int qg = 2048 + qrow + lr;

    __shared__ short Ks[2][8192];
    __shared__ short Vs[2][8192];
    __shared__ short P[4][16][72];

    const short* kbase = Kf + (size_t)h * 4096 * 128;
    const short* vbase = Vt + (size_t)h * 128 * 4096;

    bfrag8 aq[4];
    {
        const short* qp = Q + ((size_t)h * 2048 + qrow + lr) * 128 + lg * 8;
#pragma unroll
        for (int dt = 0; dt < 4; ++dt) aq[dt] = *(const bfrag8*)(qp + dt * 32);
    }
    facc4 o[8];
#pragma unroll
    for (int n = 0; n < 8; ++n) o[n] = (facc4){0.f, 0.f, 0.f, 0.f};
    float m = -1e30f, l = 0.f;

    auto stage = [&](int buf, int t0) {
#pragma unroll
        for (int it = 0; it < 4; ++it) {
            int rk = it * 16 + (tid >> 4);
            int ck = (tid & 15) ^ (rk & 7);
            GL2LDS(kbase + (size_t)(t0 + rk) * 128 + ck * 8,
                   &Ks[buf][it * 2048 + tid * 8]);
            int rv = it * 32 + (tid >> 3);
            int cv = (tid & 7) ^ (rv & 7);
            GL2LDS(vbase + (size_t)rv * 4096 + t0 + cv * 8,
                   &Vs[buf][it * 2048 + tid * 8]);
        }
    };

    auto process = [&](int buf, int t0) {
        facc4 s[4];
#pragma unroll
        for (int j = 0; j < 4; ++j) {
            s[j] = (facc4){0.f, 0.f, 0.f, 0.f};
            int r = j * 16 + lr;
#pragma unroll
            for (int dt = 0; dt < 4; ++dt) {
                bfrag8 k = *(const bfrag8*)&Ks[buf][r * 128 + (((dt * 4 + lg) ^ (r & 7)) * 8)];
                s[j] = MFMA16(k, aq[dt], s[j]);
            }
        }
        float mx = m;
#pragma unroll
        for (int j = 0; j < 4; ++j)
#pragma unroll
            for (int r = 0; r < 4; ++r) {
                int ki = t0 + j * 16 + lg * 4 + r;
                if (ki > qg) s[j][r] = -1e30f;
                mx = fmaxf(mx, s[j][r]);
            }
        mx = fmaxf(mx, __shfl_xor(mx, 16));
        mx = fmaxf(mx, __shfl_xor(mx, 32));
        if (__any(mx > m + 8.f)) {
            float alpha = __expf(m - mx);
            m = mx;
            l *= alpha;
            float ab[4];
#pragma unroll
            for (int r = 0; r < 4; ++r) ab[r] = __shfl(alpha, lg * 4 + r);
#pragma unroll
            for (int n = 0; n < 8; ++n) {
                o[n][0] *= ab[0]; o[n][1] *= ab[1]; o[n][2] *= ab[2]; o[n][3] *= ab[3];
            }
        }
        float ps = 0.f;
#pragma unroll
        for (int j = 0; j < 4; ++j)
#pragma unroll
            for (int r = 0; r < 4; ++r) {
                s[j][r] = __expf(s[j][r] - m);
                ps += s[j][r];
            }
        ps += __shfl_xor(ps, 16);
        ps += __shfl_xor(ps, 32);
        l += ps;
        unsigned* prow = (unsigned*)&P[wave][lr][0];
#pragma unroll
        for (int j = 0; j < 4; ++j) {
            prow[j * 8 + lg * 2]     = pack_bf2(s[j][0], s[j][1]);
            prow[j * 8 + lg * 2 + 1] = pack_bf2(s[j][2], s[j][3]);
        }
        bfrag8 ap0 = *(const bfrag8*)&P[wave][lr][lg * 8];
        bfrag8 ap1 = *(const bfrag8*)&P[wave][lr][32 + lg * 8];
#pragma unroll
        for (int n = 0; n < 8; ++n) {
            int rv = n * 16 + lr;
            bfrag8 v0 = *(const bfrag8*)&Vs[buf][rv * 64 + (((lg) ^ (rv & 7)) * 8)];
            bfrag8 v1 = *(const bfrag8*)&Vs[buf][rv * 64 + (((4 + lg) ^ (rv & 7)) * 8)];
            o[n] = MFMA16(ap0, v0, o[n]);
            o[n] = MFMA16(ap1, v1, o[n]);
        }
    };

    int NT = (2048 + qb + 64) >> 6;
    int i0 = z ? (NT >> 1) : 0;
    int i1 = z ? NT : (NT >> 1);

    stage(0, i0 * 64);
    __syncthreads();
    int buf = 0;
    for (int i = i0; i < i1; ++i) {
        if (i + 1 < i1) stage(buf ^ 1, (i + 1) * 64);
        process(buf, i * 64);
        __syncthreads();
        buf ^= 1;
    }

#pragma unroll
    for (int n = 0; n < 8; ++n)
#pragma unroll
        for (int r = 0; r < 4; ++r)
            Op[(size_t)(z * 2048 + qrow + lg * 4 + r) * 2048 + h * 128 + n * 16 + lr] = o[n][r];
    if (lg == 0) {
        Ml[((size_t)z * 16 + h) * 2048 + qrow + lr] = m;
        Ll[((size_t)z * 16 + h) * 2048 + qrow + lr] = l;
    }
}

__global__ __launch_bounds__(256) void attn_combine(const float* __restrict__ Op,
                                                    const float* __restrict__ Ml,
                                                    const float* __restrict__ Ll,
                                                    short* __restrict__ Ob) {
    int row = blockIdx.x, t = threadIdx.x;
    int col0 = t * 8;
    int h = col0 >> 7;
    float m0 = Ml[(size_t)h * 2048 + row], m1 = Ml[(size_t)(16 + h) * 2048 + row];
    float l0 = Ll[(size_t)h * 2048 + row], l1 = Ll[(size_t)(16 + h) * 2048 + row];
    float mm = fmaxf(m0, m1);
    float a0 = __expf(m0 - mm), a1 = __expf(m1 - mm);
    float inv = 1.f / (l0 * a0 + l1 * a1);
    a0 *= inv; a1 *= inv;
    const float* p0 = Op + (size_t)row * 2048 + col0;
    const float* p1 = Op + (size_t)(2048 + row) * 2048 + col0;
    float4 x0 = *(const float4*)p0, x1 = *(const float4*)(p0 + 4);
    float4 y0 = *(const float4*)p1, y1 = *(const float4*)(p1 + 4);
    bfrag8 ov;
    ov[0] = f2bf(x0.x * a0 + y0.x * a1); ov[1] = f2bf(x0.y * a0 + y0.y * a1);
    ov[2] = f2bf(x0.z * a0 + y0.z * a1); ov[3] = f2bf(x0.w * a0 + y0.w * a1);
    ov[4] = f2bf(x1.x * a0 + y1.x * a1); ov[5] = f2bf(x1.y * a0 + y1.y * a1);
    ov[6] = f2bf(x1.z * a0 + y1.z * a1); ov[7] = f2bf(x1.w * a0 + y1.w * a1);
    *(bfrag8*)(Ob + (size_t)row * 2048 + col0) = ov;
}

// ---------------- silu(g)*u over fused [2048][16384] bf16 (g|u halves) ----------------
__global__ __launch_bounds__(256) void silu_fused_kernel(const short* __restrict__ f,
                                                         short* __restrict__ out) {
    size_t v = (size_t)blockIdx.x * 256 + threadIdx.x;
    int r = (int)(v >> 10);
    int c = (int)(v & 1023) * 8;
    bfrag8 g = *(const bfrag8*)(f + (size_t)r * 16384 + c);
    bfrag8 u = *(const bfrag8*)(f + (size_t)r * 16384 + 8192 + c);
    bfrag8 o;
#pragma unroll
    for (int j = 0; j < 8; ++j) {
        float gf = bf2f(g[j]), uf = bf2f(u[j]);
        o[j] = f2bf(gf / (1.f + __expf(-gf)) * uf);
    }
    *(bfrag8*)(out + v * 8) = o;
}

// ---------------- orchestration ----------------
extern "C" void kernel_launch(void* const* d_in, const int* in_sizes, int n_in,
                              void* d_out, int out_size, void* d_ws, size_t ws_size,
                              hipStream_t stream) {
    const int*   ids   = (const int*)d_in[0];
    const float* emb   = (const float*)d_in[1];
    const float* Wq    = (const float*)d_in[2];
    const float* Wk    = (const float*)d_in[3];
    const float* Wv    = (const float*)d_in[4];
    const float* Wo    = (const float*)d_in[5];
    const float* Wg    = (const float*)d_in[6];
    const float* Wu    = (const float*)d_in[7];
    const float* Wd    = (const float*)d_in[8];
    const float* ln1   = (const float*)d_in[9];
    const float* ln2   = (const float*)d_in[10];
    const float* fnorm = (const float*)d_in[11];
    const float* lmh   = (const float*)d_in[12];
    const float* kc    = (const float*)d_in[13];
    const float* vc    = (const float*)d_in[14];
    float* logits = (float*)d_out;

    char* ws = (char*)d_ws;
    float* hbuf   = (float*)(ws + ((size_t)0 << 20));    // 16 MB f32 residual
    short* xb     = (short*)(ws + ((size_t)16 << 20));   // 8 MB bf16 normed x
    float* qkvbuf = (float*)(ws + ((size_t)24 << 20));   // 32 MB f32; attn partials; Wd split-K partials
    short* Ob     = (short*)(ws + ((size_t)56 << 20));   // 8 MB bf16 attn out
    short* wt     = (short*)(ws + ((size_t)64 << 20));   // 64 MB bf16 transposed weights
    short* Qb     = (short*)(ws + ((size_t)128 << 20));  // 8 MB
    short* Kf     = (short*)(ws + ((size_t)136 << 20));  // 16 MB
    short* Vt     = (short*)(ws + ((size_t)152 << 20));  // 16 MB
    short* fbuf   = (short*)(ws + ((size_t)168 << 20));  // 64 MB bf16 [2048][16384] gate|up
    short* gb     = (short*)(ws + ((size_t)232 << 20));  // 32 MB bf16 silu out
    float* mlb    = (float*)(ws + ((size_t)264 << 20));  // 0.5 MB Ml+Ll  (high water 265 MB)
    float* Mlp    = mlb;
    float* Llp    = mlb + 2 * 16 * 2048;
    float* sk0    = qkvbuf;                              // Wd split-K partial 0 (16 MB)
    float* sk1    = qkvbuf + (size_t)4 * 1024 * 1024;    // partial 1
    short* lmwt   = (short*)(ws + ((size_t)64 << 20));   // 131 MB, reuses wt..fbuf (dead then)

    embed_kernel<<<2048, 256, 0, stream>>>(ids, emb, hbuf);

    for (int l = 0; l < 2; ++l) {
        const float* wq  = Wq + (size_t)l * 2048 * 2048;
        const float* wk  = Wk + (size_t)l * 2048 * 1024;
        const float* wv  = Wv + (size_t)l * 2048 * 1024;
        const float* wo  = Wo + (size_t)l * 2048 * 2048;
        const float* wg  = Wg + (size_t)l * 2048 * 8192;
        const float* wu  = Wu + (size_t)l * 2048 * 8192;
        const float* wd  = Wd + (size_t)l * 8192 * 2048;
        const float* l1  = ln1 + (size_t)l * 2048;
        const float* l2  = ln2 + (size_t)l * 2048;
        const float* kcl = kc + (size_t)l * 16 * 2048 * 128;
        const float* vcl = vc + (size_t)l * 16 * 2048 * 128;

        rmsnorm_bf16_kernel<<<2048, 256, 0, stream>>>(hbuf, l1, xb);
        wconv_kernel<<<dim3(32, 32), 256, 0, stream>>>(wq, wt, 2048, 2048);
        wconv_kernel<<<dim3(32, 16), 256, 0, stream>>>(wk, wt + (size_t)2048 * 2048, 2048, 1024);
        wconv_kernel<<<dim3(32, 16), 256, 0, stream>>>(wv, wt + (size_t)3072 * 2048, 2048, 1024);
        gemmR<0><<<dim3(16, 32), 256, 0, stream>>>(xb, wt, qkvbuf, 2048, 2048, 4096);
        prep_q_kernel<<<dim3(16, 2048), 128, 0, stream>>>(qkvbuf, Qb);
        prep_k_kernel<<<dim3(16, 4096), 128, 0, stream>>>(kcl, qkvbuf, Kf);
        prep_v_kernel<<<dim3(16, 64), 256, 0, stream>>>(vcl, qkvbuf, Vt);
        attn_kernel<<<dim3(16, 32, 2), 256, 0, stream>>>(Qb, Kf, Vt, qkvbuf, Mlp, Llp);
        attn_combine<<<2048, 256, 0, stream>>>(qkvbuf, Mlp, Llp, Ob);
        wconv_kernel<<<dim3(32, 32), 256, 0, stream>>>(wo, wt, 2048, 2048);
        gemmR<1><<<dim3(16, 16), 256, 0, stream>>>(Ob, wt, hbuf, 2048, 2048, 2048);
        rmsnorm_bf16_kernel<<<2048, 256, 0, stream>>>(hbuf, l2, xb);
        // fused gate|up: wt rows [0,8192) = gate, [8192,16384) = up
        wconv_kernel<<<dim3(32, 128), 256, 0, stream>>>(wg, wt, 2048, 8192);
        wconv_kernel<<<dim3(32, 128), 256, 0, stream>>>(wu, wt + (size_t)8192 * 2048, 2048, 8192);
        gemmB<2><<<dim3(8, 64), 512, 0, stream>>>(xb, wt, (float*)fbuf, 2048, 16384);
        silu_fused_kernel<<<8192, 256, 0, stream>>>(fbuf, gb);
        wconv_kernel<<<dim3(128, 32), 256, 0, stream>>>(wd, wt, 8192, 2048);
        // Wd split-K x2: 512 blocks each -> 2 blocks/CU residency
        gemmR<0><<<dim3(16, 16), 256, 0, stream>>>(gb, wt, sk0, 4096, 8192, 2048);
        gemmR<0><<<dim3(16, 16), 256, 0, stream>>>(gb + 4096, wt + 4096, sk1, 4096, 8192, 2048);
        add2_kernel<<<4096, 256, 0, stream>>>(hbuf, sk0, sk1);
    }
    rmsnorm_bf16_kernel<<<2048, 256, 0, stream>>>(hbuf, fnorm, xb);
    wconv_kernel<<<dim3(32, 500), 256, 0, stream>>>(lmh, lmwt, 2048, 32000);
    // A/B: lm_head on the 2-blocks/CU 128^2 ring (vs gemmB 41% plateau)
    gemmR<0><<<dim3(16, 250), 256, 0, stream>>>(xb, lmwt, logits, 2048, 2048, 32000);
}

// Round 13
// 1535.545 us; speedup vs baseline: 1.0614x; 1.0614x over previous
//
#include <hip/hip_runtime.h>

typedef __attribute__((ext_vector_type(8))) short bfrag8;   // 8 x bf16 (4 VGPRs)
typedef __attribute__((ext_vector_type(4))) short bfrag4;   // 4 x bf16
typedef __attribute__((ext_vector_type(4))) float facc4;    // 4 x f32 accum

#define DEV_INLINE __device__ __forceinline__

DEV_INLINE short f2bf(float f) {
    union { float f; unsigned u; } x; x.f = f;
    unsigned r = (x.u + 0x7FFFu + ((x.u >> 16) & 1u)) >> 16;
    return (short)r;
}

DEV_INLINE float bf2f(short s) {
    union { unsigned u; float f; } x;
    x.u = ((unsigned)(unsigned short)s) << 16;
    return x.f;
}

DEV_INLINE unsigned pack_bf2(float a, float b) {
    return (unsigned)(unsigned short)f2bf(a) | ((unsigned)(unsigned short)f2bf(b) << 16);
}

// async global->LDS, 16B per lane; dest = wave-uniform base + lane*16
#define GL2LDS(gp, lp) __builtin_amdgcn_global_load_lds( \
    (const __attribute__((address_space(1))) void*)(gp), \
    (__attribute__((address_space(3))) void*)(lp), 16, 0, 0)

#define MFMA16(a, b, c) __builtin_amdgcn_mfma_f32_16x16x32_bf16((a), (b), (c), 0, 0, 0)

// ---------------- embedding gather ----------------
__global__ __launch_bounds__(256) void embed_kernel(const int* __restrict__ ids,
                                                    const float* __restrict__ emb,
                                                    float* __restrict__ h) {
    int s = blockIdx.x;
    int id = ids[s];
    const float* src = emb + (size_t)id * 2048;
    float* dst = h + (size_t)s * 2048;
    int t = threadIdx.x;
    float4 a = *(const float4*)(src + t * 8);
    float4 b = *(const float4*)(src + t * 8 + 4);
    *(float4*)(dst + t * 8) = a;
    *(float4*)(dst + t * 8 + 4) = b;
}

// ---------------- RMSNorm rows of 2048, bf16 out ----------------
__global__ __launch_bounds__(256) void rmsnorm_bf16_kernel(const float* __restrict__ in,
                                                           const float* __restrict__ w,
                                                           short* __restrict__ out) {
    int row = blockIdx.x;
    const float* x = in + (size_t)row * 2048;
    short* y = out + (size_t)row * 2048;
    int t = threadIdx.x;
    float4 a = *(const float4*)(x + t * 8);
    float4 b = *(const float4*)(x + t * 8 + 4);
    float ss = a.x*a.x + a.y*a.y + a.z*a.z + a.w*a.w
             + b.x*b.x + b.y*b.y + b.z*b.z + b.w*b.w;
#pragma unroll
    for (int off = 32; off >= 1; off >>= 1) ss += __shfl_xor(ss, off);
    __shared__ float red[4];
    if ((t & 63) == 0) red[t >> 6] = ss;
    __syncthreads();
    float tot = red[0] + red[1] + red[2] + red[3];
    float sc = rsqrtf(tot * (1.0f / 2048.0f) + 1e-6f);
    float4 wa = *(const float4*)(w + t * 8);
    float4 wb = *(const float4*)(w + t * 8 + 4);
    bfrag8 o;
    o[0] = f2bf(a.x * sc * wa.x); o[1] = f2bf(a.y * sc * wa.y);
    o[2] = f2bf(a.z * sc * wa.z); o[3] = f2bf(a.w * sc * wa.w);
    o[4] = f2bf(b.x * sc * wb.x); o[5] = f2bf(b.y * sc * wb.y);
    o[6] = f2bf(b.z * sc * wb.z); o[7] = f2bf(b.w * sc * wb.w);
    *(bfrag8*)(y + t * 8) = o;
}

// ---------------- weight transpose-convert: W[K][N] f32 -> Wt[N][K] bf16 ----------------
__global__ __launch_bounds__(256) void wconv_kernel(const float* __restrict__ W,
                                                    short* __restrict__ Wt,
                                                    int K, int N) {
    __shared__ short Lt[64][72];
    int k0 = blockIdx.x * 64, n0 = blockIdx.y * 64;
    int tid = threadIdx.x;
    int r = tid >> 4, c = (tid & 15) * 4;
#pragma unroll
    for (int j = 0; j < 4; ++j) {
        int k = r + j * 16;
        float4 v = *(const float4*)(W + (size_t)(k0 + k) * N + n0 + c);
        Lt[c + 0][k] = f2bf(v.x); Lt[c + 1][k] = f2bf(v.y);
        Lt[c + 2][k] = f2bf(v.z); Lt[c + 3][k] = f2bf(v.w);
    }
    __syncthreads();
    int n = tid >> 3, kk = (tid & 7) * 8;
#pragma unroll
    for (int j = 0; j < 2; ++j)
        *(bfrag8*)(Wt + (size_t)(n0 + n + j * 32) * K + k0 + kk) = *(const bfrag8*)&Lt[n + j * 32][kk];
}

// ---------------- GEMM ring-4 256x256 (big-N): C = A * Bt^T ----------------
// Measured-best: 512 thr / 8 waves (2Mx4N), BK=32, 4-slot ring, depth-3
// prefetch, counted vmcnt(8/4/0), one barrier/tile, chunk-XOR swizzle, setprio.
template<int OUT>
__global__ __launch_bounds__(512, 1) void gemmB(const short* __restrict__ A,
                                                const short* __restrict__ Bt,
                                                float* __restrict__ C,
                                                int K, int N) {
    constexpr int ASLOT = 256 * 64;      // bytes per ring slot
    constexpr int BOFF = 4 * ASLOT;
    __shared__ short lds[65536];         // 128 KB
    char* ldsb = (char*)lds;
    int tid = threadIdx.x;
    int lane = tid & 63, wave = tid >> 6;
    int wm = wave >> 2, wn = wave & 3;
    int lr = lane & 15, lg = lane >> 4;

    int gx = gridDim.x;
    int nwg = gx * gridDim.y;
    int b = blockIdx.y * gx + blockIdx.x;
    int q8 = nwg >> 3, r8 = nwg & 7;
    int xcd = b & 7, idx = b >> 3;
    int lb = (xcd < r8) ? (xcd * (q8 + 1) + idx) : (r8 * (q8 + 1) + (xcd - r8) * q8 + idx);
    int bm = (lb % gx) * 256, bn = (lb / gx) * 256;

    facc4 acc[8][4];
#pragma unroll
    for (int m = 0; m < 8; ++m)
#pragma unroll
        for (int n = 0; n < 4; ++n) acc[m][n] = (facc4){0.f, 0.f, 0.f, 0.f};

    int rs = tid >> 2;
    int cs = (tid & 3) ^ ((rs >> 1) & 3);
    const size_t sK = (size_t)K;
    const short* Ag0 = A + (size_t)(bm + rs) * sK + cs * 8;
    const short* Ag1 = A + (size_t)(bm + rs + 128) * sK + cs * 8;
    const short* Bg0 = Bt + (size_t)(bn + rs) * sK + cs * 8;
    const short* Bg1 = Bt + (size_t)(bn + rs + 128) * sK + cs * 8;

    auto stage = [&](int u) {
        int sl = u & 3;
        int ko = u * 32;
        char* Ad = ldsb + sl * ASLOT + tid * 16;
        char* Bd = ldsb + BOFF + sl * ASLOT + tid * 16;
        GL2LDS(Ag0 + ko, Ad);
        GL2LDS(Ag1 + ko, Ad + 8192);
        GL2LDS(Bg0 + ko, Bd);
        GL2LDS(Bg1 + ko, Bd + 8192);
    };

    int NT = K >> 5;
    stage(0); stage(1); stage(2);

    int arow[8], brow[4];
#pragma unroll
    for (int m = 0; m < 8; ++m) arow[m] = wm * 128 + m * 16 + lr;
#pragma unroll
    for (int n = 0; n < 4; ++n) brow[n] = wn * 64 + n * 16 + lr;

    for (int t = 0; t < NT; ++t) {
        if (t < NT - 2)       asm volatile("s_waitcnt vmcnt(8)" ::: "memory");
        else if (t == NT - 2) asm volatile("s_waitcnt vmcnt(4)" ::: "memory");
        else                  asm volatile("s_waitcnt vmcnt(0)" ::: "memory");
        __builtin_amdgcn_s_barrier();
        __builtin_amdgcn_sched_barrier(0);
        const char* Ab = ldsb + (t & 3) * ASLOT;
        const char* Bb = ldsb + BOFF + (t & 3) * ASLOT;
        bfrag8 af[8], bf[4];
#pragma unroll
        for (int m = 0; m < 8; ++m) {
            int r = arow[m];
            af[m] = *(const bfrag8*)(Ab + r * 64 + ((lg ^ ((r >> 1) & 3)) << 4));
        }
#pragma unroll
        for (int n = 0; n < 4; ++n) {
            int r = brow[n];
            bf[n] = *(const bfrag8*)(Bb + r * 64 + ((lg ^ ((r >> 1) & 3)) << 4));
        }
        if (t + 3 < NT) stage(t + 3);
        __builtin_amdgcn_s_setprio(1);
#pragma unroll
        for (int m = 0; m < 8; ++m)
#pragma unroll
            for (int n = 0; n < 4; ++n)
                acc[m][n] = MFMA16(af[m], bf[n], acc[m][n]);
        __builtin_amdgcn_s_setprio(0);
    }

    int crow = bm + wm * 128 + lg * 4;
    int ccol = bn + wn * 64 + lr;
#pragma unroll
    for (int m = 0; m < 8; ++m)
#pragma unroll
        for (int n = 0; n < 4; ++n)
#pragma unroll
            for (int r = 0; r < 4; ++r) {
                size_t ci = (size_t)(crow + m * 16 + r) * N + ccol + n * 16;
                if constexpr (OUT == 0)      C[ci] = acc[m][n][r];
                else if constexpr (OUT == 1) C[ci] = C[ci] + acc[m][n][r];
                else                         ((short*)C)[ci] = f2bf(acc[m][n][r]);
            }
}

// ---------------- GEMM ring-4 128x128 (small shapes) ----------------
// 256 thr / 4 waves (2Mx2N), BK=32, 4-slot ring, 64KB LDS, 2 blocks/CU.
// ldk = row stride (elements); K = extent to process (split-K capable).
template<int OUT>
__global__ __launch_bounds__(256, 2) void gemmR(const short* __restrict__ A,
                                                const short* __restrict__ Bt,
                                                float* __restrict__ C,
                                                int K, int ldk, int N) {
    constexpr int ASLOT = 128 * 64;
    constexpr int BOFF = 4 * ASLOT;
    __shared__ short lds[4 * 256 * 32];  // 64 KB
    char* ldsb = (char*)lds;
    int tid = threadIdx.x;
    int lane = tid & 63, wave = tid >> 6;
    int wm = wave >> 1, wn = wave & 1;
    int lr = lane & 15, lg = lane >> 4;

    int gx = gridDim.x;
    int nwg = gx * gridDim.y;
    int b = blockIdx.y * gx + blockIdx.x;
    int q8 = nwg >> 3, r8 = nwg & 7;
    int xcd = b & 7, idx = b >> 3;
    int lb = (xcd < r8) ? (xcd * (q8 + 1) + idx) : (r8 * (q8 + 1) + (xcd - r8) * q8 + idx);
    int bm = (lb % gx) * 128, bn = (lb / gx) * 128;

    facc4 acc[4][4];
#pragma unroll
    for (int m = 0; m < 4; ++m)
#pragma unroll
        for (int n = 0; n < 4; ++n) acc[m][n] = (facc4){0.f, 0.f, 0.f, 0.f};

    int rs = tid >> 2;
    int cs = (tid & 3) ^ ((rs >> 1) & 3);
    const size_t sK = (size_t)ldk;
    const short* Ag0 = A + (size_t)(bm + rs) * sK + cs * 8;
    const short* Ag1 = A + (size_t)(bm + rs + 64) * sK + cs * 8;
    const short* Bg0 = Bt + (size_t)(bn + rs) * sK + cs * 8;
    const short* Bg1 = Bt + (size_t)(bn + rs + 64) * sK + cs * 8;

    auto stage = [&](int u) {
        int sl = u & 3;
        int ko = u * 32;
        char* Ad = ldsb + sl * ASLOT + tid * 16;
        char* Bd = ldsb + BOFF + sl * ASLOT + tid * 16;
        GL2LDS(Ag0 + ko, Ad);
        GL2LDS(Ag1 + ko, Ad + 4096);
        GL2LDS(Bg0 + ko, Bd);
        GL2LDS(Bg1 + ko, Bd + 4096);
    };

    int NT = K >> 5;
    stage(0); stage(1); stage(2);

    int arow[4], brow[4];
#pragma unroll
    for (int m = 0; m < 4; ++m) arow[m] = wm * 64 + m * 16 + lr;
#pragma unroll
    for (int n = 0; n < 4; ++n) brow[n] = wn * 64 + n * 16 + lr;

    for (int t = 0; t < NT; ++t) {
        if (t < NT - 2)       asm volatile("s_waitcnt vmcnt(8)" ::: "memory");
        else if (t == NT - 2) asm volatile("s_waitcnt vmcnt(4)" ::: "memory");
        else                  asm volatile("s_waitcnt vmcnt(0)" ::: "memory");
        __builtin_amdgcn_s_barrier();
        __builtin_amdgcn_sched_barrier(0);
        const char* Ab = ldsb + (t & 3) * ASLOT;
        const char* Bb = ldsb + BOFF + (t & 3) * ASLOT;
        bfrag8 af[4], bf[4];
#pragma unroll
        for (int m = 0; m < 4; ++m) {
            int r = arow[m];
            af[m] = *(const bfrag8*)(Ab + r * 64 + ((lg ^ ((r >> 1) & 3)) << 4));
        }
#pragma unroll
        for (int n = 0; n < 4; ++n) {
            int r = brow[n];
            bf[n] = *(const bfrag8*)(Bb + r * 64 + ((lg ^ ((r >> 1) & 3)) << 4));
        }
        if (t + 3 < NT) stage(t + 3);
        __builtin_amdgcn_s_setprio(1);
#pragma unroll
        for (int m = 0; m < 4; ++m)
#pragma unroll
            for (int n = 0; n < 4; ++n)
                acc[m][n] = MFMA16(af[m], bf[n], acc[m][n]);
        __builtin_amdgcn_s_setprio(0);
    }

    int crow = bm + wm * 64 + lg * 4;
    int ccol = bn + wn * 64 + lr;
#pragma unroll
    for (int m = 0; m < 4; ++m)
#pragma unroll
        for (int n = 0; n < 4; ++n)
#pragma unroll
            for (int r = 0; r < 4; ++r) {
                size_t ci = (size_t)(crow + m * 16 + r) * N + ccol + n * 16;
                if constexpr (OUT == 0)      C[ci] = acc[m][n][r];
                else if constexpr (OUT == 1) C[ci] = C[ci] + acc[m][n][r];
                else                         ((short*)C)[ci] = f2bf(acc[m][n][r]);
            }
}

// ---------------- residual += p0 + p1 (split-K combine) ----------------
__global__ __launch_bounds__(256) void add2_kernel(float* __restrict__ h,
                                                   const float* __restrict__ p0,
                                                   const float* __restrict__ p1) {
    size_t i = ((size_t)blockIdx.x * 256 + threadIdx.x) * 4;
    float4 a = *(const float4*)(h + i);
    float4 x = *(const float4*)(p0 + i);
    float4 y = *(const float4*)(p1 + i);
    a.x += x.x + y.x; a.y += x.y + y.y; a.z += x.z + y.z; a.w += x.w + y.w;
    *(float4*)(h + i) = a;
}

// ---------------- RoPE ----------------
#define ROPE_C 0.20762050593046010f   // log2(10000)/64
#define INV2PI 0.15915494309189535f
#define TWOPI  6.283185307179586f
#define QK_SCALE 0.08838834764831845f // 1/sqrt(128), folded into Q

DEV_INLINE void rope_sc(float pos, int j, float* s, float* c) {
    float f = pos * exp2f(-(float)j * ROPE_C);
    float r = f * INV2PI;
    r -= floorf(r);
    __sincosf(r * TWOPI, s, c);
}

// batched x4: grid (16, 512)
__global__ __launch_bounds__(128) void prep_q_kernel(const float* __restrict__ qkv,
                                                     short* __restrict__ Qb) {
    int h = blockIdx.x, d = threadIdx.x;
    int s0 = blockIdx.y * 4;
#pragma unroll
    for (int i = 0; i < 4; ++i) {
        int s = s0 + i;
        const float* src = qkv + (size_t)s * 4096 + h * 128;
        float x = src[d], xp = src[d ^ 64];
        float sn, c;
        rope_sc((float)(2048 + s), d & 63, &sn, &c);
        float o = (d < 64) ? (x * c - xp * sn) : (x * c + xp * sn);
        Qb[((size_t)h * 2048 + s) * 128 + d] = f2bf(o * QK_SCALE);
    }
}

// batched x8: grid (16, 512)
__global__ __launch_bounds__(128) void prep_k_kernel(const float* __restrict__ kc,
                                                     const float* __restrict__ qkv,
                                                     short* __restrict__ Kf) {
    int h = blockIdx.x, d = threadIdx.x;
    int t0 = blockIdx.y * 8;
#pragma unroll
    for (int i = 0; i < 8; ++i) {
        int t = t0 + i;
        float x, xp;
        if (t < 2048) {
            const float* src = kc + ((size_t)h * 2048 + t) * 128;
            x = src[d]; xp = src[d ^ 64];
        } else {
            const float* src = qkv + (size_t)(t - 2048) * 4096 + 2048 + (h >> 1) * 128;
            x = src[d]; xp = src[d ^ 64];
        }
        float sn, c;
        rope_sc((float)t, d & 63, &sn, &c);
        float o = (d < 64) ? (x * c - xp * sn) : (x * c + xp * sn);
        Kf[((size_t)h * 4096 + t) * 128 + d] = f2bf(o);
    }
}

__global__ __launch_bounds__(256) void prep_v_kernel(const float* __restrict__ vc,
                                                     const float* __restrict__ qkv,
                                                     short* __restrict__ Vt) {
    int h = blockIdx.x;
    int t0 = blockIdx.y * 64;
    __shared__ short Lt[128][72];
    int tid = threadIdx.x;
    int r = tid >> 2;
    int c0 = (tid & 3) * 32;
    int t = t0 + r;
    const float* src = (t < 2048)
        ? vc + ((size_t)h * 2048 + t) * 128 + c0
        : qkv + (size_t)(t - 2048) * 4096 + 3072 + (h >> 1) * 128 + c0;
#pragma unroll
    for (int i = 0; i < 32; i += 4) {
        float4 v = *(const float4*)(src + i);
        Lt[c0 + i + 0][r] = f2bf(v.x);
        Lt[c0 + i + 1][r] = f2bf(v.y);
        Lt[c0 + i + 2][r] = f2bf(v.z);
        Lt[c0 + i + 3][r] = f2bf(v.w);
    }
    __syncthreads();
    int d = tid >> 1;
    int hh = (tid & 1) * 32;
    short* dst = Vt + ((size_t)h * 128 + d) * 4096 + t0 + hh;
    const short* srcl = &Lt[d][hh];
#pragma unroll
    for (int i = 0; i < 32; i += 8)
        *(bfrag8*)(dst + i) = *(const bfrag8*)(srcl + i);
}

// ---------------- flash attention v4: KVBLK=64 ----------------
__global__ __launch_bounds__(256, 2) void attn_kernel(const short* __restrict__ Q,
                                                      const short* __restrict__ Kf,
                                                      const short* __restrict__ Vt,
                                                      float* __restrict__ Op,
                                                      float* __restrict__ Ml,
                                                      float* __restrict__ Ll) {
    int h = blockIdx.x;
    int qb = blockIdx.y * 64;
    int z = blockIdx.z;
    int tid = threadIdx.x;
    int lane = tid & 63, wave = tid >> 6;
    int lr = lane & 15, lg = lane >> 4;
    int qrow = qb + wave * 16;
    int qg = 2048 + qrow + lr;

    __shared__ short Ks[2][8192];
    __shared__ short Vs[2][8192];
    __shared__ short P[4][16][72];

    const short* kbase = Kf + (size_t)h * 4096 * 128;
    const short* vbase = Vt + (size_t)h * 128 * 4096;

    bfrag8 aq[4];
    {
        const short* qp = Q + ((size_t)h * 2048 + qrow + lr) * 128 + lg * 8;
#pragma unroll
        for (int dt = 0; dt < 4; ++dt) aq[dt] = *(const bfrag8*)(qp + dt * 32);
    }
    facc4 o[8];
#pragma unroll
    for (int n = 0; n < 8; ++n) o[n] = (facc4){0.f, 0.f, 0.f, 0.f};
    float m = -1e30f, l = 0.f;

    auto stage = [&](int buf, int t0) {
#pragma unroll
        for (int it = 0; it < 4; ++it) {
            int rk = it * 16 + (tid >> 4);
            int ck = (tid & 15) ^ (rk & 7);
            GL2LDS(kbase + (size_t)(t0 + rk) * 128 + ck * 8,
                   &Ks[buf][it * 2048 + tid * 8]);
            int rv = it * 32 + (tid >> 3);
            int cv = (tid & 7) ^ (rv & 7);
            GL2LDS(vbase + (size_t)rv * 4096 + t0 + cv * 8,
                   &Vs[buf][it * 2048 + tid * 8]);
        }
    };

    auto process = [&](int buf, int t0) {
        facc4 s[4];
#pragma unroll
        for (int j = 0; j < 4; ++j) {
            s[j] = (facc4){0.f, 0.f, 0.f, 0.f};
            int r = j * 16 + lr;
#pragma unroll
            for (int dt = 0; dt < 4; ++dt) {
                bfrag8 k = *(const bfrag8*)&Ks[buf][r * 128 + (((dt * 4 + lg) ^ (r & 7)) * 8)];
                s[j] = MFMA16(k, aq[dt], s[j]);
            }
        }
        float mx = m;
#pragma unroll
        for (int j = 0; j < 4; ++j)
#pragma unroll
            for (int r = 0; r < 4; ++r) {
                int ki = t0 + j * 16 + lg * 4 + r;
                if (ki > qg) s[j][r] = -1e30f;
                mx = fmaxf(mx, s[j][r]);
            }
        mx = fmaxf(mx, __shfl_xor(mx, 16));
        mx = fmaxf(mx, __shfl_xor(mx, 32));
        if (__any(mx > m + 8.f)) {
            float alpha = __expf(m - mx);
            m = mx;
            l *= alpha;
            float ab[4];
#pragma unroll
            for (int r = 0; r < 4; ++r) ab[r] = __shfl(alpha, lg * 4 + r);
#pragma unroll
            for (int n = 0; n < 8; ++n) {
                o[n][0] *= ab[0]; o[n][1] *= ab[1]; o[n][2] *= ab[2]; o[n][3] *= ab[3];
            }
        }
        float ps = 0.f;
#pragma unroll
        for (int j = 0; j < 4; ++j)
#pragma unroll
            for (int r = 0; r < 4; ++r) {
                s[j][r] = __expf(s[j][r] - m);
                ps += s[j][r];
            }
        ps += __shfl_xor(ps, 16);
        ps += __shfl_xor(ps, 32);
        l += ps;
        unsigned* prow = (unsigned*)&P[wave][lr][0];
#pragma unroll
        for (int j = 0; j < 4; ++j) {
            prow[j * 8 + lg * 2]     = pack_bf2(s[j][0], s[j][1]);
            prow[j * 8 + lg * 2 + 1] = pack_bf2(s[j][2], s[j][3]);
        }
        bfrag8 ap0 = *(const bfrag8*)&P[wave][lr][lg * 8];
        bfrag8 ap1 = *(const bfrag8*)&P[wave][lr][32 + lg * 8];
#pragma unroll
        for (int n = 0; n < 8; ++n) {
            int rv = n * 16 + lr;
            bfrag8 v0 = *(const bfrag8*)&Vs[buf][rv * 64 + (((lg) ^ (rv & 7)) * 8)];
            bfrag8 v1 = *(const bfrag8*)&Vs[buf][rv * 64 + (((4 + lg) ^ (rv & 7)) * 8)];
            o[n] = MFMA16(ap0, v0, o[n]);
            o[n] = MFMA16(ap1, v1, o[n]);
        }
    };

    int NT = (2048 + qb + 64) >> 6;
    int i0 = z ? (NT >> 1) : 0;
    int i1 = z ? NT : (NT >> 1);

    stage(0, i0 * 64);
    __syncthreads();
    int buf = 0;
    for (int i = i0; i < i1; ++i) {
        if (i + 1 < i1) stage(buf ^ 1, (i + 1) * 64);
        process(buf, i * 64);
        __syncthreads();
        buf ^= 1;
    }

#pragma unroll
    for (int n = 0; n < 8; ++n)
#pragma unroll
        for (int r = 0; r < 4; ++r)
            Op[(size_t)(z * 2048 + qrow + lg * 4 + r) * 2048 + h * 128 + n * 16 + lr] = o[n][r];
    if (lg == 0) {
        Ml[((size_t)z * 16 + h) * 2048 + qrow + lr] = m;
        Ll[((size_t)z * 16 + h) * 2048 + qrow + lr] = l;
    }
}

__global__ __launch_bounds__(256) void attn_combine(const float* __restrict__ Op,
                                                    const float* __restrict__ Ml,
                                                    const float* __restrict__ Ll,
                                                    short* __restrict__ Ob) {
    int row = blockIdx.x, t = threadIdx.x;
    int col0 = t * 8;
    int h = col0 >> 7;
    float m0 = Ml[(size_t)h * 2048 + row], m1 = Ml[(size_t)(16 + h) * 2048 + row];
    float l0 = Ll[(size_t)h * 2048 + row], l1 = Ll[(size_t)(16 + h) * 2048 + row];
    float mm = fmaxf(m0, m1);
    float a0 = __expf(m0 - mm), a1 = __expf(m1 - mm);
    float inv = 1.f / (l0 * a0 + l1 * a1);
    a0 *= inv; a1 *= inv;
    const float* p0 = Op + (size_t)row * 2048 + col0;
    const float* p1 = Op + (size_t)(2048 + row) * 2048 + col0;
    float4 x0 = *(const float4*)p0, x1 = *(const float4*)(p0 + 4);
    float4 y0 = *(const float4*)p1, y1 = *(const float4*)(p1 + 4);
    bfrag8 ov;
    ov[0] = f2bf(x0.x * a0 + y0.x * a1); ov[1] = f2bf(x0.y * a0 + y0.y * a1);
    ov[2] = f2bf(x0.z * a0 + y0.z * a1); ov[3] = f2bf(x0.w * a0 + y0.w * a1);
    ov[4] = f2bf(x1.x * a0 + y1.x * a1); ov[5] = f2bf(x1.y * a0 + y1.y * a1);
    ov[6] = f2bf(x1.z * a0 + y1.z * a1); ov[7] = f2bf(x1.w * a0 + y1.w * a1);
    *(bfrag8*)(Ob + (size_t)row * 2048 + col0) = ov;
}

// ---------------- silu(g)*u over fused [2048][16384] bf16 (g|u halves) ----------------
__global__ __launch_bounds__(256) void silu_fused_kernel(const short* __restrict__ f,
                                                         short* __restrict__ out) {
    size_t v = (size_t)blockIdx.x * 256 + threadIdx.x;
    int r = (int)(v >> 10);
    int c = (int)(v & 1023) * 8;
    bfrag8 g = *(const bfrag8*)(f + (size_t)r * 16384 + c);
    bfrag8 u = *(const bfrag8*)(f + (size_t)r * 16384 + 8192 + c);
    bfrag8 o;
#pragma unroll
    for (int j = 0; j < 8; ++j) {
        float gf = bf2f(g[j]), uf = bf2f(u[j]);
        o[j] = f2bf(gf / (1.f + __expf(-gf)) * uf);
    }
    *(bfrag8*)(out + v * 8) = o;
}

// ---------------- orchestration ----------------
extern "C" void kernel_launch(void* const* d_in, const int* in_sizes, int n_in,
                              void* d_out, int out_size, void* d_ws, size_t ws_size,
                              hipStream_t stream) {
    const int*   ids   = (const int*)d_in[0];
    const float* emb   = (const float*)d_in[1];
    const float* Wq    = (const float*)d_in[2];
    const float* Wk    = (const float*)d_in[3];
    const float* Wv    = (const float*)d_in[4];
    const float* Wo    = (const float*)d_in[5];
    const float* Wg    = (const float*)d_in[6];
    const float* Wu    = (const float*)d_in[7];
    const float* Wd    = (const float*)d_in[8];
    const float* ln1   = (const float*)d_in[9];
    const float* ln2   = (const float*)d_in[10];
    const float* fnorm = (const float*)d_in[11];
    const float* lmh   = (const float*)d_in[12];
    const float* kc    = (const float*)d_in[13];
    const float* vc    = (const float*)d_in[14];
    float* logits = (float*)d_out;

    char* ws = (char*)d_ws;
    float* hbuf   = (float*)(ws + ((size_t)0 << 20));    // 16 MB f32 residual
    short* xb     = (short*)(ws + ((size_t)16 << 20));   // 8 MB bf16 normed x
    float* qkvbuf = (float*)(ws + ((size_t)24 << 20));   // 32 MB f32; attn partials; split-K partials
    short* Ob     = (short*)(ws + ((size_t)56 << 20));   // 8 MB bf16 attn out
    short* wt     = (short*)(ws + ((size_t)64 << 20));   // 64 MB bf16 transposed weights
    short* Qb     = (short*)(ws + ((size_t)128 << 20));  // 8 MB
    short* Kf     = (short*)(ws + ((size_t)136 << 20));  // 16 MB
    short* Vt     = (short*)(ws + ((size_t)152 << 20));  // 16 MB
    short* fbuf   = (short*)(ws + ((size_t)168 << 20));  // 64 MB bf16 [2048][16384] gate|up
    short* gb     = (short*)(ws + ((size_t)232 << 20));  // 32 MB bf16 silu out
    float* mlb    = (float*)(ws + ((size_t)264 << 20));  // 0.5 MB Ml+Ll  (high water 265 MB)
    float* Mlp    = mlb;
    float* Llp    = mlb + 2 * 16 * 2048;
    float* sk0    = qkvbuf;                              // Wd split-K partial 0 (16 MB)
    float* sk1    = qkvbuf + (size_t)4 * 1024 * 1024;    // partial 1
    short* lmwt   = (short*)(ws + ((size_t)64 << 20));   // 131 MB, reuses wt..fbuf (dead then)

    embed_kernel<<<2048, 256, 0, stream>>>(ids, emb, hbuf);

    for (int l = 0; l < 2; ++l) {
        const float* wq  = Wq + (size_t)l * 2048 * 2048;
        const float* wk  = Wk + (size_t)l * 2048 * 1024;
        const float* wv  = Wv + (size_t)l * 2048 * 1024;
        const float* wo  = Wo + (size_t)l * 2048 * 2048;
        const float* wg  = Wg + (size_t)l * 2048 * 8192;
        const float* wu  = Wu + (size_t)l * 2048 * 8192;
        const float* wd  = Wd + (size_t)l * 8192 * 2048;
        const float* l1  = ln1 + (size_t)l * 2048;
        const float* l2  = ln2 + (size_t)l * 2048;
        const float* kcl = kc + (size_t)l * 16 * 2048 * 128;
        const float* vcl = vc + (size_t)l * 16 * 2048 * 128;

        rmsnorm_bf16_kernel<<<2048, 256, 0, stream>>>(hbuf, l1, xb);
        wconv_kernel<<<dim3(32, 32), 256, 0, stream>>>(wq, wt, 2048, 2048);
        wconv_kernel<<<dim3(32, 16), 256, 0, stream>>>(wk, wt + (size_t)2048 * 2048, 2048, 1024);
        wconv_kernel<<<dim3(32, 16), 256, 0, stream>>>(wv, wt + (size_t)3072 * 2048, 2048, 1024);
        gemmR<0><<<dim3(16, 32), 256, 0, stream>>>(xb, wt, qkvbuf, 2048, 2048, 4096);
        prep_q_kernel<<<dim3(16, 512), 128, 0, stream>>>(qkvbuf, Qb);
        prep_k_kernel<<<dim3(16, 512), 128, 0, stream>>>(kcl, qkvbuf, Kf);
        prep_v_kernel<<<dim3(16, 64), 256, 0, stream>>>(vcl, qkvbuf, Vt);
        attn_kernel<<<dim3(16, 32, 2), 256, 0, stream>>>(Qb, Kf, Vt, qkvbuf, Mlp, Llp);
        attn_combine<<<2048, 256, 0, stream>>>(qkvbuf, Mlp, Llp, Ob);
        wconv_kernel<<<dim3(32, 32), 256, 0, stream>>>(wo, wt, 2048, 2048);
        gemmR<1><<<dim3(16, 16), 256, 0, stream>>>(Ob, wt, hbuf, 2048, 2048, 2048);
        rmsnorm_bf16_kernel<<<2048, 256, 0, stream>>>(hbuf, l2, xb);
        // fused gate|up: wt rows [0,8192) = gate, [8192,16384) = up
        wconv_kernel<<<dim3(32, 128), 256, 0, stream>>>(wg, wt, 2048, 8192);
        wconv_kernel<<<dim3(32, 128), 256, 0, stream>>>(wu, wt + (size_t)8192 * 2048, 2048, 8192);
        gemmB<2><<<dim3(8, 64), 512, 0, stream>>>(xb, wt, (float*)fbuf, 2048, 16384);
        silu_fused_kernel<<<8192, 256, 0, stream>>>(fbuf, gb);
        wconv_kernel<<<dim3(128, 32), 256, 0, stream>>>(wd, wt, 8192, 2048);
        // Wd split-K x2: 512 blocks each -> 2 blocks/CU residency
        gemmR<0><<<dim3(16, 16), 256, 0, stream>>>(gb, wt, sk0, 4096, 8192, 2048);
        gemmR<0><<<dim3(16, 16), 256, 0, stream>>>(gb + 4096, wt + 4096, sk1, 4096, 8192, 2048);
        add2_kernel<<<4096, 256, 0, stream>>>(hbuf, sk0, sk1);
    }
    rmsnorm_bf16_kernel<<<2048, 256, 0, stream>>>(hbuf, fnorm, xb);
    wconv_kernel<<<dim3(32, 500), 256, 0, stream>>>(lmh, lmwt, 2048, 32000);
    gemmB<0><<<dim3(8, 125), 512, 0, stream>>>(xb, lmwt, logits, 2048, 32000);
}